// Round 2
// baseline (791.260 us; speedup 1.0000x reference)
//
#include <hip/hip_runtime.h>
#include <hip/hip_bf16.h>
#include <cstddef>
#include <cstdint>

#define T_TOK 1024
#define HDIM  2048
#define NEXP  64
#define IDIM  768
#define TOPK  8

using f32x4 = __attribute__((ext_vector_type(4))) float;
using s16x8 = __attribute__((ext_vector_type(8))) short;

// ---- workspace layout (bytes) ----
static constexpr size_t XBF_OFF = 0;                                   // bf16 X: 4 MiB
static constexpr size_t CNT_OFF = (size_t)T_TOK * HDIM * 2;            // 64 ints
static constexpr size_t OFF_OFF = CNT_OFF + 256;                       // 65 ints
static constexpr size_t Q_OFF   = CNT_OFF + 768;                       // 2 ints (work queues)
static constexpr size_t TOK_OFF = CNT_OFF + 1024;                      // 64*1024 ints
static constexpr size_t WT_OFF  = TOK_OFF + (size_t)NEXP * T_TOK * 4;  // 64*1024 floats
static constexpr size_t HH_OFF  = WT_OFF  + (size_t)NEXP * T_TOK * 4;  // 8192*768 bf16

__device__ __forceinline__ short f2bf(float f) {
  union { __hip_bfloat16 b; short s; } u;
  u.b = __float2bfloat16(f);
  return u.s;
}

__device__ __forceinline__ void gl_lds16(const void* g, void* l) {
  __builtin_amdgcn_global_load_lds(
      (const __attribute__((address_space(1))) unsigned int*)g,
      (__attribute__((address_space(3))) unsigned int*)l, 16, 0, 0);
}
__device__ __forceinline__ void barrier_raw() {
  asm volatile("" ::: "memory");
  __builtin_amdgcn_s_barrier();
  asm volatile("" ::: "memory");
}
#define WAIT_VM6()   asm volatile("s_waitcnt vmcnt(6)" ::: "memory")
#define WAIT_LGKM0() asm volatile("s_waitcnt lgkmcnt(0)" ::: "memory")

// ---------------- x fp32 -> bf16 ----------------
__global__ __launch_bounds__(256) void convert_x_kernel(
    const float* __restrict__ X, __hip_bfloat16* __restrict__ Xb) {
  const int i = (blockIdx.x * 256 + threadIdx.x) * 8;
  f32x4 a = *(const f32x4*)(X + i);
  f32x4 b = *(const f32x4*)(X + i + 4);
  union { short h[8]; int4 q; } u;
#pragma unroll
  for (int c = 0; c < 4; ++c) { u.h[c] = f2bf(a[c]); u.h[4 + c] = f2bf(b[c]); }
  *(int4*)((char*)Xb + (size_t)i * 2) = u.q;
}

// ---------------- router ----------------
__global__ __launch_bounds__(256) void router_kernel(
    const float* __restrict__ X, const float* __restrict__ GW,
    int* __restrict__ cnt, int* __restrict__ tokl, float* __restrict__ wtl) {
  __shared__ float xs[HDIM];
  __shared__ float lg[NEXP];
  const int t = blockIdx.x;
  const int tid = threadIdx.x;
  const f32x4* xr = (const f32x4*)(X + (size_t)t * HDIM);
#pragma unroll
  for (int i = 0; i < 2; ++i) {
    f32x4 v = xr[tid + i * 256];
    *(f32x4*)&xs[(tid + i * 256) * 4] = v;
  }
  __syncthreads();
  const int wid = tid >> 6, lane = tid & 63;
  for (int ee = 0; ee < 16; ++ee) {
    const int e = wid * 16 + ee;
    const float* g = GW + (size_t)e * HDIM;
    float acc = 0.f;
    for (int i = lane; i < HDIM; i += 64) acc += xs[i] * g[i];
#pragma unroll
    for (int s = 32; s; s >>= 1) acc += __shfl_xor(acc, s);
    if (lane == 0) lg[e] = acc;
  }
  __syncthreads();
  if (tid < 64) {
    const float v = lg[tid];
    float m = v;
#pragma unroll
    for (int s = 32; s; s >>= 1) m = fmaxf(m, __shfl_xor(m, s));
    const float p = expf(v - m);
    float den = p;
#pragma unroll
    for (int s = 32; s; s >>= 1) den += __shfl_xor(den, s);
    float work = p / den;
    float my_v = 0.f; int my_e = 0;
    float topsum = 0.f;
#pragma unroll
    for (int k = 0; k < TOPK; ++k) {
      float mv = work;
#pragma unroll
      for (int s = 32; s; s >>= 1) mv = fmaxf(mv, __shfl_xor(mv, s));
      unsigned long long ball = __ballot(work == mv);
      const int idx = __ffsll(ball) - 1;   // lowest index on ties (matches lax.top_k)
      topsum += mv;
      if (tid == k) { my_v = mv; my_e = idx; }
      if (tid == idx) work = -1.f;
    }
    if (tid < TOPK) {
      const float w = my_v / topsum;
      const int slot = atomicAdd(&cnt[my_e], 1);
      tokl[my_e * T_TOK + slot] = t;
      wtl[my_e * T_TOK + slot] = w;
    }
  }
}

// ---------------- prefix scan ----------------
__global__ void scan_kernel(const int* __restrict__ cnt, int* __restrict__ offs) {
  if (threadIdx.x == 0) {
    int a = 0;
    for (int e = 0; e < NEXP; ++e) { offs[e] = a; a += cnt[e]; }
    offs[NEXP] = a;
  }
}

// ---------------- gate+up GEMM + SwiGLU ----------------
// item = (e, ti, nj); BM=128, BN=32 (per matrix), BK=32; fp32 W staged via
// global_load_lds into granule-swizzled LDS, bf16 convert on fragment read.
#define GU_NJ    24
#define GU_MAXTI 4
#define GU_ITEMS (NEXP * GU_MAXTI * GU_NJ)
#define GU_BUF   8192
#define GU_NS    (HDIM / 32)

__global__ __launch_bounds__(256, 3) void gateup_kernel(
    const __hip_bfloat16* __restrict__ Xb,
    const float* __restrict__ WG, const float* __restrict__ WU,
    const int* __restrict__ cnt, const int* __restrict__ offs,
    const int* __restrict__ tokl, const float* __restrict__ wtl,
    __hip_bfloat16* __restrict__ Hh, int* __restrict__ q) {
  __shared__ __align__(16) char sB[3 * GU_BUF];
  __shared__ int sItem;
  const int tid  = threadIdx.x;
  const int lane = tid & 63;
  const int wid  = tid >> 6;
  const int m = lane >> 4;          // k-group within fragment
  const int c = lane & 15;          // row/col within fragment
  const int wrow = (wid >> 1) * 64;
  const int wb4  = (wid & 1) * 4;   // wave col base granule
  // per-lane ds-read address parts (j&3 periodic in swizzle)
  int adsl[4];
#pragma unroll
  for (int jj = 0; jj < 4; ++jj) {
    const int slot = wb4 + ((c >> 2) ^ ((m ^ jj) & 3));
    adsl[jj] = 1024 * m + slot * 16 + (c & 3) * 4;
  }
  // staging geometry: wave -> (mat, 16-row half); 2 insts of 8 rows each
  const int mat = wid >> 1;
  const int kq  = wid & 1;
  const int kA  = kq * 16 + (lane >> 3);
  const int kB  = kA + 8;
  const int n4A = (lane & 7) ^ ((kA ^ (kA >> 3)) & 3);
  const int n4B = (lane & 7) ^ ((kB ^ (kB >> 3)) & 3);
  const int dA  = mat * 4096 + kq * 16 * 128;
  const int dB  = dA + 1024;

  for (;;) {
    __syncthreads();
    if (tid == 0) sItem = atomicAdd(q, 1);
    __syncthreads();
    const int it = sItem;
    if (it >= GU_ITEMS) break;
    const int e   = it / (GU_MAXTI * GU_NJ);
    const int rem = it - e * (GU_MAXTI * GU_NJ);
    const int ti  = rem / GU_NJ;
    const int nj  = rem - ti * GU_NJ;
    const int ne  = cnt[e];
    if (ti * 128 >= ne) continue;
    const int nrows = min(128, ne - ti * 128);
    const int cbase = offs[e] + ti * 128;
    const int nb    = nj * 32;
    const int tbase = e * T_TOK + ti * 128;

    const __hip_bfloat16* ap0;
    const __hip_bfloat16* ap1;
    const __hip_bfloat16* ap2;
    const __hip_bfloat16* ap3;
    {
      const int r0 = wrow + 0 * 16 + c, r1 = wrow + 1 * 16 + c;
      const int r2 = wrow + 2 * 16 + c, r3 = wrow + 3 * 16 + c;
      ap0 = Xb + (size_t)tokl[tbase + min(r0, nrows - 1)] * HDIM + m * 8;
      ap1 = Xb + (size_t)tokl[tbase + min(r1, nrows - 1)] * HDIM + m * 8;
      ap2 = Xb + (size_t)tokl[tbase + min(r2, nrows - 1)] * HDIM + m * 8;
      ap3 = Xb + (size_t)tokl[tbase + min(r3, nrows - 1)] * HDIM + m * 8;
    }
    const float* WM = mat ? WU : WG;
    const size_t wbo = (size_t)e * HDIM * IDIM + nb;
    const float* spA = WM + wbo + (size_t)kA * IDIM + n4A * 4;
    const float* spB = WM + wbo + (size_t)kB * IDIM + n4B * 4;

    f32x4 accg[4], accu[4];
#pragma unroll
    for (int i = 0; i < 4; ++i)
#pragma unroll
      for (int r = 0; r < 4; ++r) { accg[i][r] = 0.f; accu[i][r] = 0.f; }

    int bufb = 0, sbase = 2 * GU_BUF;
    // prologue: stage tiles 0,1 ; load A(0)
    gl_lds16(spA, sB + dA); gl_lds16(spB, sB + dB);
    spA += 32 * IDIM; spB += 32 * IDIM;
    gl_lds16(spA, sB + GU_BUF + dA); gl_lds16(spB, sB + GU_BUF + dB);
    spA += 32 * IDIM; spB += 32 * IDIM;
    s16x8 afE[4], afO[4];
    afE[0] = *(const s16x8*)ap0; afE[1] = *(const s16x8*)ap1;
    afE[2] = *(const s16x8*)ap2; afE[3] = *(const s16x8*)ap3;

    auto body = [&](int t, s16x8 (&afC)[4], s16x8 (&afN)[4]) {
      if (t + 2 < GU_NS) {
        gl_lds16(spA, sB + sbase + dA);
        gl_lds16(spB, sB + sbase + dB);
        spA += 32 * IDIM; spB += 32 * IDIM;
      }
      if (t + 1 < GU_NS) {
        ap0 += 32; ap1 += 32; ap2 += 32; ap3 += 32;
        afN[0] = *(const s16x8*)ap0; afN[1] = *(const s16x8*)ap1;
        afN[2] = *(const s16x8*)ap2; afN[3] = *(const s16x8*)ap3;
      }
      WAIT_VM6();
      barrier_raw();
      s16x8 bg, bu;
#pragma unroll
      for (int j = 0; j < 8; ++j) {
        const float vg = *(const float*)(sB + bufb + adsl[j & 3] + 128 * j);
        const float vu = *(const float*)(sB + bufb + 4096 + adsl[j & 3] + 128 * j);
        bg[j] = f2bf(vg); bu[j] = f2bf(vu);
      }
      WAIT_LGKM0();
      __builtin_amdgcn_sched_barrier(0);
      barrier_raw();
#pragma unroll
      for (int mi = 0; mi < 4; ++mi) {
        accg[mi] = __builtin_amdgcn_mfma_f32_16x16x32_bf16(afC[mi], bg, accg[mi], 0, 0, 0);
        accu[mi] = __builtin_amdgcn_mfma_f32_16x16x32_bf16(afC[mi], bu, accu[mi], 0, 0, 0);
      }
      bufb  = (bufb  == 2 * GU_BUF) ? 0 : bufb  + GU_BUF;
      sbase = (sbase == 2 * GU_BUF) ? 0 : sbase + GU_BUF;
    };
    for (int t = 0; t < GU_NS; t += 2) { body(t, afE, afO); body(t + 1, afO, afE); }

    // epilogue: silu(g)*u * route_weight -> bf16 Hh (compact rows)
    const int colg = nb + (wid & 1) * 16 + c;
    __hip_bfloat16* hp = Hh + (size_t)cbase * IDIM + colg;
#pragma unroll
    for (int mi = 0; mi < 4; ++mi) {
      const int rb = wrow + mi * 16 + m * 4;
      const f32x4 wt4 = *(const f32x4*)&wtl[tbase + rb];
#pragma unroll
      for (int rr = 0; rr < 4; ++rr) {
        const int row = rb + rr;
        if (row < nrows) {
          const float g = accg[mi][rr], u = accu[mi][rr];
          const float h = (g / (1.f + __expf(-g))) * u * wt4[rr];
          hp[(size_t)row * IDIM] = __float2bfloat16(h);
        }
      }
    }
  }
}

// ---------------- down GEMM + scatter ----------------
// item = (e, ti, nj); BM=128, BN=64, BK=32.
#define DN_NJ    32
#define DN_MAXTI 4
#define DN_ITEMS (NEXP * DN_MAXTI * DN_NJ)
#define DN_BUF   8192
#define DN_NS    (IDIM / 32)

__global__ __launch_bounds__(256, 3) void down_kernel(
    const __hip_bfloat16* __restrict__ Hh, const float* __restrict__ WD,
    const int* __restrict__ cnt, const int* __restrict__ offs,
    const int* __restrict__ tokl, float* __restrict__ Out, int* __restrict__ q) {
  __shared__ __align__(16) char sB[3 * DN_BUF];
  __shared__ int sItem;
  const int tid  = threadIdx.x;
  const int lane = tid & 63;
  const int wid  = tid >> 6;
  const int m = lane >> 4;
  const int c = lane & 15;
  const int wrow = (wid >> 1) * 64;
  const int wcol = (wid & 1) * 32;
  int adsl[2][4];
#pragma unroll
  for (int ni = 0; ni < 2; ++ni)
#pragma unroll
    for (int jj = 0; jj < 4; ++jj) {
      const int slot = ((wcol + ni * 16) >> 2) + ((c >> 2) ^ ((m ^ jj) & 3));
      adsl[ni][jj] = 2048 * m + slot * 16 + (c & 3) * 4;
    }
  const int kA  = wid * 8 + (lane >> 4);
  const int kB  = kA + 4;
  const int n4A = (lane & 15) ^ ((kA ^ (kA >> 3)) & 3);
  const int n4B = (lane & 15) ^ ((kB ^ (kB >> 3)) & 3);
  const int dA  = wid * 8 * 256;
  const int dB  = dA + 1024;

  for (;;) {
    __syncthreads();
    if (tid == 0) sItem = atomicAdd(q, 1);
    __syncthreads();
    const int it = sItem;
    if (it >= DN_ITEMS) break;
    const int e   = it / (DN_MAXTI * DN_NJ);
    const int rem = it - e * (DN_MAXTI * DN_NJ);
    const int ti  = rem / DN_NJ;
    const int nj  = rem - ti * DN_NJ;
    const int ne  = cnt[e];
    if (ti * 128 >= ne) continue;
    const int nrows = min(128, ne - ti * 128);
    const int cbase = offs[e] + ti * 128;
    const int nb    = nj * 64;
    const int tbase = e * T_TOK + ti * 128;

    const __hip_bfloat16* ap0;
    const __hip_bfloat16* ap1;
    const __hip_bfloat16* ap2;
    const __hip_bfloat16* ap3;
    {
      const int r0 = wrow + 0 * 16 + c, r1 = wrow + 1 * 16 + c;
      const int r2 = wrow + 2 * 16 + c, r3 = wrow + 3 * 16 + c;
      ap0 = Hh + (size_t)(cbase + min(r0, nrows - 1)) * IDIM + m * 8;
      ap1 = Hh + (size_t)(cbase + min(r1, nrows - 1)) * IDIM + m * 8;
      ap2 = Hh + (size_t)(cbase + min(r2, nrows - 1)) * IDIM + m * 8;
      ap3 = Hh + (size_t)(cbase + min(r3, nrows - 1)) * IDIM + m * 8;
    }
    const size_t wbo = (size_t)e * IDIM * HDIM + nb;
    const float* spA = WD + wbo + (size_t)kA * HDIM + n4A * 4;
    const float* spB = WD + wbo + (size_t)kB * HDIM + n4B * 4;

    f32x4 acc[4][2];
#pragma unroll
    for (int i = 0; i < 4; ++i)
#pragma unroll
      for (int n = 0; n < 2; ++n)
#pragma unroll
        for (int r = 0; r < 4; ++r) acc[i][n][r] = 0.f;

    int bufb = 0, sbase = 2 * DN_BUF;
    gl_lds16(spA, sB + dA); gl_lds16(spB, sB + dB);
    spA += 32 * HDIM; spB += 32 * HDIM;
    gl_lds16(spA, sB + DN_BUF + dA); gl_lds16(spB, sB + DN_BUF + dB);
    spA += 32 * HDIM; spB += 32 * HDIM;
    s16x8 afE[4], afO[4];
    afE[0] = *(const s16x8*)ap0; afE[1] = *(const s16x8*)ap1;
    afE[2] = *(const s16x8*)ap2; afE[3] = *(const s16x8*)ap3;

    auto body = [&](int t, s16x8 (&afC)[4], s16x8 (&afN)[4]) {
      if (t + 2 < DN_NS) {
        gl_lds16(spA, sB + sbase + dA);
        gl_lds16(spB, sB + sbase + dB);
        spA += 32 * HDIM; spB += 32 * HDIM;
      }
      if (t + 1 < DN_NS) {
        ap0 += 32; ap1 += 32; ap2 += 32; ap3 += 32;
        afN[0] = *(const s16x8*)ap0; afN[1] = *(const s16x8*)ap1;
        afN[2] = *(const s16x8*)ap2; afN[3] = *(const s16x8*)ap3;
      }
      WAIT_VM6();
      barrier_raw();
      s16x8 bf[2];
#pragma unroll
      for (int ni = 0; ni < 2; ++ni)
#pragma unroll
        for (int j = 0; j < 8; ++j) {
          const float v = *(const float*)(sB + bufb + adsl[ni][j & 3] + 256 * j);
          bf[ni][j] = f2bf(v);
        }
      WAIT_LGKM0();
      __builtin_amdgcn_sched_barrier(0);
      barrier_raw();
#pragma unroll
      for (int mi = 0; mi < 4; ++mi)
#pragma unroll
        for (int ni = 0; ni < 2; ++ni)
          acc[mi][ni] = __builtin_amdgcn_mfma_f32_16x16x32_bf16(afC[mi], bf[ni], acc[mi][ni], 0, 0, 0);
      bufb  = (bufb  == 2 * DN_BUF) ? 0 : bufb  + DN_BUF;
      sbase = (sbase == 2 * DN_BUF) ? 0 : sbase + DN_BUF;
    };
    for (int t = 0; t < DN_NS; t += 2) { body(t, afE, afO); body(t + 1, afO, afE); }

    // epilogue: fp32 atomic scatter into Out
    const int colg = nb + wcol + c;
#pragma unroll
    for (int mi = 0; mi < 4; ++mi) {
      const int rb = wrow + mi * 16 + m * 4;
      const int4 tk4 = *(const int4*)&tokl[tbase + rb];
      const int tks[4] = {tk4.x, tk4.y, tk4.z, tk4.w};
#pragma unroll
      for (int rr = 0; rr < 4; ++rr) {
        const int row = rb + rr;
        if (row < nrows) {
          const int tok = tks[rr];
          atomicAdd(&Out[(size_t)tok * HDIM + colg],      acc[mi][0][rr]);
          atomicAdd(&Out[(size_t)tok * HDIM + colg + 16], acc[mi][1][rr]);
        }
      }
    }
  }
}

extern "C" void kernel_launch(void* const* d_in, const int* in_sizes, int n_in,
                              void* d_out, int out_size, void* d_ws, size_t ws_size,
                              hipStream_t stream) {
  (void)in_sizes; (void)n_in; (void)ws_size;
  const float* X  = (const float*)d_in[0];
  const float* GW = (const float*)d_in[1];
  const float* WG = (const float*)d_in[2];
  const float* WU = (const float*)d_in[3];
  const float* WD = (const float*)d_in[4];
  float* Out = (float*)d_out;
  char* ws = (char*)d_ws;

  __hip_bfloat16* Xb = (__hip_bfloat16*)(ws + XBF_OFF);
  int*   cnt  = (int*)(ws + CNT_OFF);
  int*   offs = (int*)(ws + OFF_OFF);
  int*   qq   = (int*)(ws + Q_OFF);
  int*   tokl = (int*)(ws + TOK_OFF);
  float* wtl  = (float*)(ws + WT_OFF);
  __hip_bfloat16* Hh = (__hip_bfloat16*)(ws + HH_OFF);

  hipMemsetAsync(ws + CNT_OFF, 0, 1024, stream);  // cnt + offs + queues
  hipMemsetAsync(d_out, 0, (size_t)out_size * sizeof(float), stream);

  convert_x_kernel<<<(T_TOK * HDIM) / (256 * 8), 256, 0, stream>>>(X, Xb);
  router_kernel<<<T_TOK, 256, 0, stream>>>(X, GW, cnt, tokl, wtl);
  scan_kernel<<<1, 64, 0, stream>>>(cnt, offs);
  gateup_kernel<<<1024, 256, 0, stream>>>(Xb, WG, WU, cnt, offs, tokl, wtl, Hh, qq);
  down_kernel<<<1024, 256, 0, stream>>>(Hh, WD, cnt, offs, tokl, Out, qq + 1);
}

// Round 3
// 641.704 us; speedup vs baseline: 1.2331x; 1.2331x over previous
//
#include <hip/hip_runtime.h>
#include <hip/hip_bf16.h>
#include <cstddef>
#include <cstdint>

#define T_TOK 1024
#define HDIM  2048
#define NEXP  64
#define IDIM  768
#define TOPK  8

using f32x4 = __attribute__((ext_vector_type(4))) float;
using s16x8 = __attribute__((ext_vector_type(8))) short;

// ---- workspace layout (bytes) ----
static constexpr size_t XBF_OFF = 0;                                   // bf16 X: 4 MiB
static constexpr size_t CNT_OFF = (size_t)T_TOK * HDIM * 2;            // 64 ints
static constexpr size_t OFF_OFF = CNT_OFF + 256;                       // 65 ints
static constexpr size_t Q_OFF   = CNT_OFF + 768;                       // 2 ints (work queues)
static constexpr size_t TOK_OFF = CNT_OFF + 1024;                      // 64*1024 ints
static constexpr size_t WT_OFF  = TOK_OFF + (size_t)NEXP * T_TOK * 4;  // 64*1024 floats
static constexpr size_t HH_OFF  = WT_OFF  + (size_t)NEXP * T_TOK * 4;  // 8192*768 bf16

__device__ __forceinline__ short f2bf(float f) {
  union { __hip_bfloat16 b; short s; } u;
  u.b = __float2bfloat16(f);
  return u.s;
}

__device__ __forceinline__ void gl_lds16(const void* g, void* l) {
  __builtin_amdgcn_global_load_lds(
      (const __attribute__((address_space(1))) unsigned int*)g,
      (__attribute__((address_space(3))) unsigned int*)l, 16, 0, 0);
}
__device__ __forceinline__ void barrier_raw() {
  asm volatile("" ::: "memory");
  __builtin_amdgcn_s_barrier();
  asm volatile("" ::: "memory");
}
#define WAIT_VM8()   asm volatile("s_waitcnt vmcnt(8)" ::: "memory")
#define WAIT_VM4()   asm volatile("s_waitcnt vmcnt(4)" ::: "memory")
#define WAIT_VM0()   asm volatile("s_waitcnt vmcnt(0)" ::: "memory")
#define WAIT_LGKM0() asm volatile("s_waitcnt lgkmcnt(0)" ::: "memory")

// ---------------- x fp32 -> bf16 ----------------
__global__ __launch_bounds__(256) void convert_x_kernel(
    const float* __restrict__ X, __hip_bfloat16* __restrict__ Xb) {
  const int i = (blockIdx.x * 256 + threadIdx.x) * 8;
  f32x4 a = *(const f32x4*)(X + i);
  f32x4 b = *(const f32x4*)(X + i + 4);
  union { short h[8]; int4 q; } u;
#pragma unroll
  for (int c = 0; c < 4; ++c) { u.h[c] = f2bf(a[c]); u.h[4 + c] = f2bf(b[c]); }
  *(int4*)((char*)Xb + (size_t)i * 2) = u.q;
}

// ---------------- router ----------------
__global__ __launch_bounds__(256) void router_kernel(
    const float* __restrict__ X, const float* __restrict__ GW,
    int* __restrict__ cnt, int* __restrict__ tokl, float* __restrict__ wtl) {
  __shared__ float xs[HDIM];
  __shared__ float lg[NEXP];
  const int t = blockIdx.x;
  const int tid = threadIdx.x;
  const f32x4* xr = (const f32x4*)(X + (size_t)t * HDIM);
#pragma unroll
  for (int i = 0; i < 2; ++i) {
    f32x4 v = xr[tid + i * 256];
    *(f32x4*)&xs[(tid + i * 256) * 4] = v;
  }
  __syncthreads();
  const int wid = tid >> 6, lane = tid & 63;
  for (int ee = 0; ee < 16; ++ee) {
    const int e = wid * 16 + ee;
    const float* g = GW + (size_t)e * HDIM;
    float acc = 0.f;
    for (int i = lane; i < HDIM; i += 64) acc += xs[i] * g[i];
#pragma unroll
    for (int s = 32; s; s >>= 1) acc += __shfl_xor(acc, s);
    if (lane == 0) lg[e] = acc;
  }
  __syncthreads();
  if (tid < 64) {
    const float v = lg[tid];
    float m = v;
#pragma unroll
    for (int s = 32; s; s >>= 1) m = fmaxf(m, __shfl_xor(m, s));
    const float p = expf(v - m);
    float den = p;
#pragma unroll
    for (int s = 32; s; s >>= 1) den += __shfl_xor(den, s);
    float work = p / den;
    float my_v = 0.f; int my_e = 0;
    float topsum = 0.f;
#pragma unroll
    for (int k = 0; k < TOPK; ++k) {
      float mv = work;
#pragma unroll
      for (int s = 32; s; s >>= 1) mv = fmaxf(mv, __shfl_xor(mv, s));
      unsigned long long ball = __ballot(work == mv);
      const int idx = __ffsll(ball) - 1;   // lowest index on ties (matches lax.top_k)
      topsum += mv;
      if (tid == k) { my_v = mv; my_e = idx; }
      if (tid == idx) work = -1.f;
    }
    if (tid < TOPK) {
      const float w = my_v / topsum;
      const int slot = atomicAdd(&cnt[my_e], 1);
      tokl[my_e * T_TOK + slot] = t;
      wtl[my_e * T_TOK + slot] = w;
    }
  }
}

// ---------------- prefix scan ----------------
__global__ void scan_kernel(const int* __restrict__ cnt, int* __restrict__ offs) {
  if (threadIdx.x == 0) {
    int a = 0;
    for (int e = 0; e < NEXP; ++e) { offs[e] = a; a += cnt[e]; }
    offs[NEXP] = a;
  }
}

// ================= gate+up GEMM + SwiGLU =================
// item = (e, ti, nj); BM=128, BN=32 per matrix, BK=32.
// ALL staging (A rows of Xb + fp32 W) via global_load_lds, 3 buffers of
// 16 KiB (A 8K + Bg 4K + Bu 4K), counted vmcnt(8/4/0), 4 gl_lds/wave/body.
#define GU_NJ    24
#define GU_MAXTI 2
#define GU_ITEMS (NEXP * GU_MAXTI * GU_NJ)
#define GU_NS    (HDIM / 32)
#define GU_BUFSZ 16384

__global__ __launch_bounds__(256, 3) void gateup_kernel(
    const __hip_bfloat16* __restrict__ Xb,
    const float* __restrict__ WG, const float* __restrict__ WU,
    const int* __restrict__ cnt, const int* __restrict__ offs,
    const int* __restrict__ tokl, const float* __restrict__ wtl,
    __hip_bfloat16* __restrict__ Hh, int* __restrict__ q) {
  __shared__ __align__(16) char sL[3 * GU_BUFSZ];
  __shared__ int sItem;
  const int tid  = threadIdx.x;
  const int lane = tid & 63;
  const int wid  = tid >> 6;
  const int m = lane >> 4;          // k-chunk of fragment (8 bf16 each)
  const int c = lane & 15;          // row/col within fragment
  const int wrow  = (wid >> 1) * 64;
  const int whalf = wid & 1;
  const int wb4   = whalf * 4;

  // B fragment ds-addresses (within buffer; gate at +8192, up adds +4096)
  int adsl[4];
#pragma unroll
  for (int jj = 0; jj < 4; ++jj) {
    const int slot = wb4 + ((c >> 2) ^ ((m ^ jj) & 3));
    adsl[jj] = 8192 + 1024 * m + slot * 16 + (c & 3) * 4;
  }
  // A fragment ds-addresses (row-major [128][64B], chunk XOR row&3 swizzle)
  int aoff[4];
#pragma unroll
  for (int mi = 0; mi < 4; ++mi) {
    const int row = wrow + mi * 16 + c;
    aoff[mi] = row * 64 + ((m ^ (c & 3)) << 4);
  }
  // A staging lane geometry: inst i covers rows wid*32+i*16 .. +15
  const int achunk = (lane & 3) ^ ((lane >> 2) & 3);   // pre-swizzled source chunk
  // B staging lane geometry (R2-verified): wave pair per matrix, 8 rows/inst
  const int mat = wid >> 1;
  const int kq  = wid & 1;
  const int kA  = kq * 16 + (lane >> 3), kB = kA + 8;
  const int n4A = (lane & 7) ^ ((kA ^ (kA >> 3)) & 3);
  const int n4B = (lane & 7) ^ ((kB ^ (kB >> 3)) & 3);
  const int dB0 = 8192 + mat * 4096 + kq * 2048;

  for (;;) {
    __syncthreads();
    if (tid == 0) sItem = atomicAdd(q, 1);
    __syncthreads();
    const int it = sItem;
    if (it >= GU_ITEMS) break;
    const int e   = it / (GU_MAXTI * GU_NJ);
    const int rem = it - e * (GU_MAXTI * GU_NJ);
    const int ti  = rem / GU_NJ;
    const int nj  = rem - ti * GU_NJ;
    const int ne  = cnt[e];
    if (ti * 128 >= ne) continue;
    const int nrows = min(128, ne - ti * 128);
    const int cbase = offs[e] + ti * 128;
    const int nb    = nj * 32;
    const int tbase = e * T_TOK + ti * 128;

    // per-lane global source pointers
    const __hip_bfloat16* pa0;
    const __hip_bfloat16* pa1;
    {
      const int r0 = wid * 32 + (lane >> 2);
      const int r1 = r0 + 16;
      pa0 = Xb + (size_t)tokl[tbase + min(r0, nrows - 1)] * HDIM + achunk * 8;
      pa1 = Xb + (size_t)tokl[tbase + min(r1, nrows - 1)] * HDIM + achunk * 8;
    }
    const float* WM = mat ? WU : WG;
    const size_t wbo = (size_t)e * HDIM * IDIM + nb;
    const float* pbA = WM + wbo + (size_t)kA * IDIM + n4A * 4;
    const float* pbB = WM + wbo + (size_t)kB * IDIM + n4B * 4;

    f32x4 accg[4], accu[4];
#pragma unroll
    for (int i = 0; i < 4; ++i)
#pragma unroll
      for (int r = 0; r < 4; ++r) { accg[i][r] = 0.f; accu[i][r] = 0.f; }

    const int aw0 = wid * 2048, aw1 = aw0 + 1024;
    auto issue = [&](int dst) {
      gl_lds16(pa0, sL + dst + aw0);
      gl_lds16(pa1, sL + dst + aw1);
      gl_lds16(pbA, sL + dst + dB0);
      gl_lds16(pbB, sL + dst + dB0 + 1024);
      pa0 += 32; pa1 += 32;
      pbA += 32 * IDIM; pbB += 32 * IDIM;
    };

    int cons = 0, dest = 2 * GU_BUFSZ;
    issue(0);
    issue(GU_BUFSZ);

    auto body = [&](int waitn, bool do_issue) {
      if (do_issue) {
        issue(dest);
        dest = (dest == 2 * GU_BUFSZ) ? 0 : dest + GU_BUFSZ;
      }
      if (waitn == 8) WAIT_VM8(); else if (waitn == 4) WAIT_VM4(); else WAIT_VM0();
      barrier_raw();
      s16x8 af[4];
#pragma unroll
      for (int mi = 0; mi < 4; ++mi) af[mi] = *(const s16x8*)(sL + cons + aoff[mi]);
      s16x8 bg, bu;
#pragma unroll
      for (int j = 0; j < 8; ++j) {
        bg[j] = f2bf(*(const float*)(sL + cons + adsl[j & 3] + 128 * j));
        bu[j] = f2bf(*(const float*)(sL + cons + 4096 + adsl[j & 3] + 128 * j));
      }
      WAIT_LGKM0();
      __builtin_amdgcn_sched_barrier(0);
      barrier_raw();
#pragma unroll
      for (int mi = 0; mi < 4; ++mi) {
        accg[mi] = __builtin_amdgcn_mfma_f32_16x16x32_bf16(af[mi], bg, accg[mi], 0, 0, 0);
        accu[mi] = __builtin_amdgcn_mfma_f32_16x16x32_bf16(af[mi], bu, accu[mi], 0, 0, 0);
      }
      cons = (cons == 2 * GU_BUFSZ) ? 0 : cons + GU_BUFSZ;
    };

    for (int t = 0; t < GU_NS - 2; ++t) body(8, true);
    body(4, false);
    body(0, false);

    // epilogue: silu(g)*u * route_weight -> bf16 Hh (compact rows)
    const int colg = nb + whalf * 16 + c;
    __hip_bfloat16* hp = Hh + (size_t)cbase * IDIM + colg;
#pragma unroll
    for (int mi = 0; mi < 4; ++mi) {
      const int rb = wrow + mi * 16 + m * 4;
      const f32x4 wt4 = *(const f32x4*)&wtl[tbase + rb];
#pragma unroll
      for (int rr = 0; rr < 4; ++rr) {
        const int row = rb + rr;
        if (row < nrows) {
          const float g = accg[mi][rr], u = accu[mi][rr];
          const float h = (g / (1.f + __expf(-g))) * u * wt4[rr];
          hp[(size_t)row * IDIM] = __float2bfloat16(h);
        }
      }
    }
  }
}

// ================= down GEMM + scatter =================
// item = (e, ti, nj); BM=128, BN=64, BK=32. Same staging scheme.
#define DN_NJ    32
#define DN_MAXTI 2
#define DN_ITEMS (NEXP * DN_MAXTI * DN_NJ)
#define DN_NS    (IDIM / 32)
#define DN_BUFSZ 16384

__global__ __launch_bounds__(256, 3) void down_kernel(
    const __hip_bfloat16* __restrict__ Hh, const float* __restrict__ WD,
    const int* __restrict__ cnt, const int* __restrict__ offs,
    const int* __restrict__ tokl, float* __restrict__ Out, int* __restrict__ q) {
  __shared__ __align__(16) char sL[3 * DN_BUFSZ];
  __shared__ int sItem;
  const int tid  = threadIdx.x;
  const int lane = tid & 63;
  const int wid  = tid >> 6;
  const int m = lane >> 4;
  const int c = lane & 15;
  const int wrow = (wid >> 1) * 64;
  const int wcol = (wid & 1) * 32;

  int adsl[2][4];
#pragma unroll
  for (int ni = 0; ni < 2; ++ni)
#pragma unroll
    for (int jj = 0; jj < 4; ++jj) {
      const int slot = ((wcol + ni * 16) >> 2) + ((c >> 2) ^ ((m ^ jj) & 3));
      adsl[ni][jj] = 8192 + 2048 * m + slot * 16 + (c & 3) * 4;
    }
  int aoff[4];
#pragma unroll
  for (int mi = 0; mi < 4; ++mi) {
    const int row = wrow + mi * 16 + c;
    aoff[mi] = row * 64 + ((m ^ (c & 3)) << 4);
  }
  const int achunk = (lane & 3) ^ ((lane >> 2) & 3);
  const int kA  = wid * 8 + (lane >> 4), kB = kA + 4;
  const int n4A = (lane & 15) ^ ((kA ^ (kA >> 3)) & 3);
  const int n4B = (lane & 15) ^ ((kB ^ (kB >> 3)) & 3);
  const int dB0 = 8192 + wid * 2048;

  for (;;) {
    __syncthreads();
    if (tid == 0) sItem = atomicAdd(q, 1);
    __syncthreads();
    const int it = sItem;
    if (it >= DN_ITEMS) break;
    const int e   = it / (DN_MAXTI * DN_NJ);
    const int rem = it - e * (DN_MAXTI * DN_NJ);
    const int ti  = rem / DN_NJ;
    const int nj  = rem - ti * DN_NJ;
    const int ne  = cnt[e];
    if (ti * 128 >= ne) continue;
    const int nrows = min(128, ne - ti * 128);
    const int cbase = offs[e] + ti * 128;
    const int nb    = nj * 64;
    const int tbase = e * T_TOK + ti * 128;

    const __hip_bfloat16* pa0;
    const __hip_bfloat16* pa1;
    {
      const int r0 = wid * 32 + (lane >> 2);
      const int r1 = r0 + 16;
      pa0 = Hh + (size_t)(cbase + min(r0, nrows - 1)) * IDIM + achunk * 8;
      pa1 = Hh + (size_t)(cbase + min(r1, nrows - 1)) * IDIM + achunk * 8;
    }
    const size_t wbo = (size_t)e * IDIM * HDIM + nb;
    const float* pbA = WD + wbo + (size_t)kA * HDIM + n4A * 4;
    const float* pbB = WD + wbo + (size_t)kB * HDIM + n4B * 4;

    f32x4 acc[4][2];
#pragma unroll
    for (int i = 0; i < 4; ++i)
#pragma unroll
      for (int n = 0; n < 2; ++n)
#pragma unroll
        for (int r = 0; r < 4; ++r) acc[i][n][r] = 0.f;

    const int aw0 = wid * 2048, aw1 = aw0 + 1024;
    auto issue = [&](int dst) {
      gl_lds16(pa0, sL + dst + aw0);
      gl_lds16(pa1, sL + dst + aw1);
      gl_lds16(pbA, sL + dst + dB0);
      gl_lds16(pbB, sL + dst + dB0 + 1024);
      pa0 += 32; pa1 += 32;
      pbA += 32 * HDIM; pbB += 32 * HDIM;
    };

    int cons = 0, dest = 2 * DN_BUFSZ;
    issue(0);
    issue(DN_BUFSZ);

    auto body = [&](int waitn, bool do_issue) {
      if (do_issue) {
        issue(dest);
        dest = (dest == 2 * DN_BUFSZ) ? 0 : dest + DN_BUFSZ;
      }
      if (waitn == 8) WAIT_VM8(); else if (waitn == 4) WAIT_VM4(); else WAIT_VM0();
      barrier_raw();
      s16x8 af[4];
#pragma unroll
      for (int mi = 0; mi < 4; ++mi) af[mi] = *(const s16x8*)(sL + cons + aoff[mi]);
      s16x8 bf[2];
#pragma unroll
      for (int ni = 0; ni < 2; ++ni)
#pragma unroll
        for (int j = 0; j < 8; ++j)
          bf[ni][j] = f2bf(*(const float*)(sL + cons + adsl[ni][j & 3] + 256 * j));
      WAIT_LGKM0();
      __builtin_amdgcn_sched_barrier(0);
      barrier_raw();
#pragma unroll
      for (int mi = 0; mi < 4; ++mi)
#pragma unroll
        for (int ni = 0; ni < 2; ++ni)
          acc[mi][ni] = __builtin_amdgcn_mfma_f32_16x16x32_bf16(af[mi], bf[ni], acc[mi][ni], 0, 0, 0);
      cons = (cons == 2 * DN_BUFSZ) ? 0 : cons + DN_BUFSZ;
    };

    for (int t = 0; t < DN_NS - 2; ++t) body(8, true);
    body(4, false);
    body(0, false);

    // epilogue: fp32 atomic scatter into Out
    const int colg = nb + wcol + c;
#pragma unroll
    for (int mi = 0; mi < 4; ++mi) {
      const int rb = wrow + mi * 16 + m * 4;
      const int4 tk4 = *(const int4*)&tokl[tbase + rb];
      const int tks[4] = {tk4.x, tk4.y, tk4.z, tk4.w};
#pragma unroll
      for (int rr = 0; rr < 4; ++rr) {
        const int row = rb + rr;
        if (row < nrows) {
          const int tok = tks[rr];
          atomicAdd(&Out[(size_t)tok * HDIM + colg],      acc[mi][0][rr]);
          atomicAdd(&Out[(size_t)tok * HDIM + colg + 16], acc[mi][1][rr]);
        }
      }
    }
  }
}

extern "C" void kernel_launch(void* const* d_in, const int* in_sizes, int n_in,
                              void* d_out, int out_size, void* d_ws, size_t ws_size,
                              hipStream_t stream) {
  (void)in_sizes; (void)n_in; (void)ws_size;
  const float* X  = (const float*)d_in[0];
  const float* GW = (const float*)d_in[1];
  const float* WG = (const float*)d_in[2];
  const float* WU = (const float*)d_in[3];
  const float* WD = (const float*)d_in[4];
  float* Out = (float*)d_out;
  char* ws = (char*)d_ws;

  __hip_bfloat16* Xb = (__hip_bfloat16*)(ws + XBF_OFF);
  int*   cnt  = (int*)(ws + CNT_OFF);
  int*   offs = (int*)(ws + OFF_OFF);
  int*   qq   = (int*)(ws + Q_OFF);
  int*   tokl = (int*)(ws + TOK_OFF);
  float* wtl  = (float*)(ws + WT_OFF);
  __hip_bfloat16* Hh = (__hip_bfloat16*)(ws + HH_OFF);

  hipMemsetAsync(ws + CNT_OFF, 0, 1024, stream);  // cnt + offs + queues
  hipMemsetAsync(d_out, 0, (size_t)out_size * sizeof(float), stream);

  convert_x_kernel<<<(T_TOK * HDIM) / (256 * 8), 256, 0, stream>>>(X, Xb);
  router_kernel<<<T_TOK, 256, 0, stream>>>(X, GW, cnt, tokl, wtl);
  scan_kernel<<<1, 64, 0, stream>>>(cnt, offs);
  gateup_kernel<<<768, 256, 0, stream>>>(Xb, WG, WU, cnt, offs, tokl, wtl, Hh, qq);
  down_kernel<<<768, 256, 0, stream>>>(Hh, WD, cnt, offs, tokl, Out, qq + 1);
}